// Round 3
// baseline (388.144 us; speedup 1.0000x reference)
//
#include <hip/hip_runtime.h>

#define NV 15000
#define ND 16
#define NR 3
#define NC 32
#define NFDIM 64
#define BB 2

typedef short bf16x8 __attribute__((ext_vector_type(8)));
typedef float f32x4 __attribute__((ext_vector_type(4)));
typedef unsigned short u16x8 __attribute__((ext_vector_type(8)));

// ws layout (bytes):
//   y_t  bf16 [NV][16][2][32]          : 30,720,000
//   kb   bf16 [48][4][64][8]           :    196,608
#define KB_OFF     30720000u
#define WS_NEEDED  30916608u

__device__ __forceinline__ unsigned short f2bf(float x) {
  union { float f; unsigned int u; } cv; cv.f = x;
  unsigned int u = cv.u;
  u += 0x7FFF + ((u >> 16) & 1);          // round to nearest even
  return (unsigned short)(u >> 16);
}

// y (B,NV,16,32) fp32 -> y_t (NV,16,B,32) bf16. One thread per 8 elems,
// vectorized: 2x float4 load, 1x 16B store.
__global__ void prep_y(const float* __restrict__ y, u16x8* __restrict__ yt) {
  int tid = blockIdx.x * 256 + threadIdx.x;
  if (tid >= (NV * ND * BB * NC) / 8) return;
  int o   = tid * 8;
  int v   = o >> 10;
  int rem = o & 1023;
  int d   = rem >> 6;
  int b   = (rem >> 5) & 1;
  int c0  = rem & 31;
  const f32x4* src = (const f32x4*)(y + (((b * NV + v) * ND + d) * NC + c0));
  f32x4 lo = src[0], hi = src[1];
  u16x8 r;
#pragma unroll
  for (int i = 0; i < 4; i++) { r[i] = f2bf(lo[i]); r[4 + i] = f2bf(hi[i]); }
  yt[tid] = r;
}

// kernel (3,16,32,64) fp32 -> kb in MFMA B-fragment layout with f = 4*col+ft:
// kb[((chunk*4 + ft)*64 + lane)*8 + j] = kernel[chunk][k=(lane>>4)*8+j][f=(lane&15)*4+ft]
__global__ void prep_kb(const float* __restrict__ kern, unsigned short* __restrict__ kb) {
  int t = blockIdx.x * 256 + threadIdx.x;   // [0, 48*4*64)
  if (t >= 48 * 4 * 64) return;
  int lane  = t & 63;
  int ft    = (t >> 6) & 3;
  int chunk = t >> 8;
  int q = lane >> 4;
  int f = (lane & 15) * 4 + ft;
  unsigned short* dst = kb + t * 8;
#pragma unroll
  for (int j = 0; j < 8; j++) {
    int k = q * 8 + j;
    dst[j] = f2bf(kern[(chunk * NC + k) * NFDIM + f]);
  }
}

// Main: block = 4 waves, one m-group of 16 v (32 rows m=v*2+b), waves handle
// l = lg*4 + w. Per wave: 2 m-tiles x 4 f-tiles, 48 K-steps of 16x16x32 MFMA.
// Packed indices staged in LDS; A-fragments prefetched 8-wide per 4-step group.
// launch_bounds (256,5): ~88 combined VGPR+AGPR/wave -> 5 waves/EU fits;
// (256,4) capped occupancy at 42% while both pipes sat <20% (latency-bound).
__global__ __launch_bounds__(256, 5) void sync_conv_main(
    const unsigned short* __restrict__ yt, const unsigned short* __restrict__ kb,
    const int* __restrict__ ftv, const int* __restrict__ ftd,
    const float* __restrict__ bias, float* __restrict__ out) {
  __shared__ int pidx_lds[16][49];   // packed ftv*16+ftd, padded stride

  int tid  = threadIdx.x;
  int lane = tid & 63;
  int mg   = blockIdx.x >> 2;
  int lg   = blockIdx.x & 3;
  int l    = lg * 4 + (tid >> 6);
  int vbase = mg * 16;

  // Stage packed indices: 16 v x 48 (r,d) ints, coalesced.
  for (int t = tid; t < 16 * 48; t += 256) {
    int i = t / 48, j = t - i * 48;
    int v = vbase + i; v = v < NV ? v : NV - 1;
    pidx_lds[i][j] = ftv[v * 48 + j] * 16 + (ftd[v * 48 + j] & 15);
  }
  __syncthreads();

  int q    = lane >> 4;
  int n    = lane & 15;                // A-row group / D col
  int b    = n & 1;
  int voff = n >> 1;
  int lane_elem = b * 32 + q * 8;
  const unsigned short* kb_lane = kb + lane * 8;

  f32x4 acc[2][4];
#pragma unroll
  for (int i = 0; i < 2; i++)
#pragma unroll
    for (int j = 0; j < 4; j++) acc[i][j] = (f32x4){0.f, 0.f, 0.f, 0.f};

  for (int r = 0; r < NR; r++) {
#pragma unroll
    for (int dg = 0; dg < 4; dg++) {
      // prefetch 8 A-fragments (2 mt x 4 d-steps)
      bf16x8 afr[2][4];
#pragma unroll
      for (int mt = 0; mt < 2; mt++)
#pragma unroll
        for (int ds = 0; ds < 4; ds++) {
          int p  = pidx_lds[mt * 8 + voff][r * 16 + dg * 4 + ds];
          int dd = ((p & 15) + l) & 15;
          int off = (p >> 4) * 1024 + (dd << 6) + lane_elem;
          afr[mt][ds] = *reinterpret_cast<const bf16x8*>(yt + off);
        }
#pragma unroll
      for (int ds = 0; ds < 4; ds++) {
        int d  = dg * 4 + ds;
        int dp = (d - l) & 15;
        const unsigned short* kbp = kb_lane + (r * 16 + dp) * 2048;
        bf16x8 bfr[4];
#pragma unroll
        for (int ft = 0; ft < 4; ft++)
          bfr[ft] = *reinterpret_cast<const bf16x8*>(kbp + ft * 512);
#pragma unroll
        for (int mt = 0; mt < 2; mt++)
#pragma unroll
          for (int ft = 0; ft < 4; ft++)
            acc[mt][ft] = __builtin_amdgcn_mfma_f32_16x16x32_bf16(
                afr[mt][ds], bfr[ft], acc[mt][ft], 0, 0, 0);
      }
    }
  }

  f32x4 bv = *reinterpret_cast<const f32x4*>(bias + 4 * n);

#pragma unroll
  for (int mt = 0; mt < 2; mt++) {
#pragma unroll
    for (int reg = 0; reg < 4; reg++) {
      int m  = q * 4 + reg;                      // D row
      int v  = vbase + mt * 8 + (m >> 1);
      int bb = m & 1;
      if (v < NV) {
        f32x4 x;
#pragma unroll
        for (int ft = 0; ft < 4; ft++) {
          float t = acc[mt][ft][reg] + bv[ft];   // f = 4n+ft
          x[ft] = t > 0.f ? t : 0.f;
        }
        float* dst = out + (((bb * NV + v) * ND + l) * NFDIM) + 4 * n;
        __builtin_nontemporal_store(x, (f32x4*)dst);
      }
    }
  }
}

// Slow fp32 fallback (only if ws too small).
__global__ void fallback_kernel(const float* __restrict__ y, const int* __restrict__ ftv,
                                const int* __restrict__ ftd, const float* __restrict__ kern,
                                const float* __restrict__ bias, float* __restrict__ out) {
  int idx = blockIdx.x;               // b*NV*16 + v*16 + l
  int l = idx & 15;
  int v = (idx >> 4) % NV;
  int b = idx / (NV * ND);
  int f = threadIdx.x;
  float acc = 0.f;
  for (int r = 0; r < NR; r++)
    for (int d = 0; d < ND; d++) {
      int ii = (v * NR + r) * ND + d;
      int vv = ftv[ii];
      int dd = (ftd[ii] + l) & 15;
      int dp = (d - l) & 15;
      const float* yp = y + ((b * NV + vv) * ND + dd) * NC;
      const float* kp = kern + ((r * 16 + dp) * NC) * NFDIM + f;
#pragma unroll 8
      for (int c = 0; c < NC; c++) acc += yp[c] * kp[c * NFDIM];
    }
  float x = acc + bias[f];
  out[idx * NFDIM + f] = x > 0.f ? x : 0.f;
}

extern "C" void kernel_launch(void* const* d_in, const int* in_sizes, int n_in,
                              void* d_out, int out_size, void* d_ws, size_t ws_size,
                              hipStream_t stream) {
  const float* y    = (const float*)d_in[0];
  const int*   ftv  = (const int*)d_in[1];
  const int*   ftd  = (const int*)d_in[2];
  const float* kern = (const float*)d_in[3];
  const float* bias = (const float*)d_in[4];
  float* out = (float*)d_out;

  if (ws_size >= (size_t)WS_NEEDED) {
    char* ws = (char*)d_ws;
    unsigned short* yt = (unsigned short*)ws;
    unsigned short* kb = (unsigned short*)(ws + KB_OFF);

    prep_y<<<(NV * ND * BB * NC / 8 + 255) / 256, 256, 0, stream>>>(y, (u16x8*)yt);
    prep_kb<<<(48 * 4 * 64 + 255) / 256, 256, 0, stream>>>(kern, kb);
    // 938 m-groups (16 v each) x 4 l-groups = 3752 blocks x 4 waves
    sync_conv_main<<<3752, 256, 0, stream>>>(yt, kb, ftv, ftd, bias, out);
  } else {
    fallback_kernel<<<BB * NV * ND, NFDIM, 0, stream>>>(y, ftv, ftd, kern, bias, out);
  }
}

// Round 4
// 376.102 us; speedup vs baseline: 1.0320x; 1.0320x over previous
//
#include <hip/hip_runtime.h>

#define NV 15000
#define ND 16
#define NR 3
#define NC 32
#define NFDIM 64
#define BB 2

typedef short bf16x8 __attribute__((ext_vector_type(8)));
typedef float f32x4 __attribute__((ext_vector_type(4)));
typedef unsigned short u16x8 __attribute__((ext_vector_type(8)));

// ws layout (bytes):
//   y_t  bf16 [NV][16][2][32]          : 30,720,000
//   kb   bf16 [48][4][64][8]           :    196,608
#define KB_OFF     30720000u
#define WS_NEEDED  30916608u

__device__ __forceinline__ unsigned short f2bf(float x) {
  union { float f; unsigned int u; } cv; cv.f = x;
  unsigned int u = cv.u;
  u += 0x7FFF + ((u >> 16) & 1);          // round to nearest even
  return (unsigned short)(u >> 16);
}

// y (B,NV,16,32) fp32 -> y_t (NV,16,B,32) bf16. One thread per 8 elems.
__global__ void prep_y(const float* __restrict__ y, u16x8* __restrict__ yt) {
  int tid = blockIdx.x * 256 + threadIdx.x;
  if (tid >= (NV * ND * BB * NC) / 8) return;
  int o   = tid * 8;
  int v   = o >> 10;
  int rem = o & 1023;
  int d   = rem >> 6;
  int b   = (rem >> 5) & 1;
  int c0  = rem & 31;
  const f32x4* src = (const f32x4*)(y + (((b * NV + v) * ND + d) * NC + c0));
  f32x4 lo = src[0], hi = src[1];
  u16x8 r;
#pragma unroll
  for (int i = 0; i < 4; i++) { r[i] = f2bf(lo[i]); r[4 + i] = f2bf(hi[i]); }
  yt[tid] = r;
}

// kernel (3,16,32,64) fp32 -> kb in MFMA B-fragment layout with f = 4*col+ft:
// kb[((chunk*4 + ft)*64 + lane)*8 + j] = kernel[chunk][k=(lane>>4)*8+j][f=(lane&15)*4+ft]
__global__ void prep_kb(const float* __restrict__ kern, unsigned short* __restrict__ kb) {
  int t = blockIdx.x * 256 + threadIdx.x;   // [0, 48*4*64)
  if (t >= 48 * 4 * 64) return;
  int lane  = t & 63;
  int ft    = (t >> 6) & 3;
  int chunk = t >> 8;
  int q = lane >> 4;
  int f = (lane & 15) * 4 + ft;
  unsigned short* dst = kb + t * 8;
#pragma unroll
  for (int j = 0; j < 8; j++) {
    int k = q * 8 + j;
    dst[j] = f2bf(kern[(chunk * NC + k) * NFDIM + f]);
  }
}

// Main: block = 4 waves, m-group of 16 v (32 rows m=v*2+b), wave w handles
// l = lg*4 + w. Per wave: 2 m-tiles x 4 f-tiles, 48 K-steps.
// R4: explicit software pipeline — BOTH A and B fragments double-buffered in
// registers, batch = 2 K-steps, loads for batch i+1 issued before the MFMAs
// of batch i. (R2/R3 loaded B immediately before use -> ~4 L1/L2 round-trip
// stalls per dg group; both pipes sat at 17%.)
__global__ __launch_bounds__(256, 3) void sync_conv_main(
    const unsigned short* __restrict__ yt, const unsigned short* __restrict__ kb,
    const int* __restrict__ ftv, const int* __restrict__ ftd,
    const float* __restrict__ bias, float* __restrict__ out) {
  __shared__ int pidx_lds[16][49];   // packed ftv*16+ftd, padded stride

  int tid  = threadIdx.x;
  int lane = tid & 63;
  int mg   = blockIdx.x >> 2;
  int lg   = blockIdx.x & 3;
  int l    = lg * 4 + (tid >> 6);
  int vbase = mg * 16;

  for (int t = tid; t < 16 * 48; t += 256) {
    int i = t / 48, j = t - i * 48;
    int v = vbase + i; v = v < NV ? v : NV - 1;
    pidx_lds[i][j] = ftv[v * 48 + j] * 16 + (ftd[v * 48 + j] & 15);
  }
  __syncthreads();

  int q    = lane >> 4;
  int n    = lane & 15;
  int b    = n & 1;
  int voff = n >> 1;
  int lane_elem = b * 32 + q * 8;
  const unsigned short* kb_lane = kb + lane * 8;

  f32x4 acc[2][4];
#pragma unroll
  for (int i = 0; i < 2; i++)
#pragma unroll
    for (int j = 0; j < 4; j++) acc[i][j] = (f32x4){0.f, 0.f, 0.f, 0.f};

  // Double-buffered fragment registers.
  bf16x8 bufA[2][2][2];   // [parity][mt][ds]   32 VGPR
  bf16x8 bufB[2][2][4];   // [parity][ds][ft]   64 VGPR

  // Batch = 2 K-steps (k = batch*2 + ds, k = r*16+d). 24 batches.
  auto load_batch = [&](int bidx, int par) {
    int k0 = bidx * 2;
#pragma unroll
    for (int ds = 0; ds < 2; ds++) {
      int k = k0 + ds;
      int r = k >> 4;
      int dp = ((k & 15) - l) & 15;
      const unsigned short* kbp = kb_lane + (r * 16 + dp) * 2048;
#pragma unroll
      for (int ft = 0; ft < 4; ft++)
        bufB[par][ds][ft] = *reinterpret_cast<const bf16x8*>(kbp + ft * 512);
#pragma unroll
      for (int mt = 0; mt < 2; mt++) {
        int p  = pidx_lds[mt * 8 + voff][k];
        int dd = ((p & 15) + l) & 15;
        int off = (p >> 4) * 1024 + (dd << 6) + lane_elem;
        bufA[par][mt][ds] = *reinterpret_cast<const bf16x8*>(yt + off);
      }
    }
  };
  auto compute_batch = [&](int par) {
#pragma unroll
    for (int ds = 0; ds < 2; ds++)
#pragma unroll
      for (int mt = 0; mt < 2; mt++)
#pragma unroll
        for (int ft = 0; ft < 4; ft++)
          acc[mt][ft] = __builtin_amdgcn_mfma_f32_16x16x32_bf16(
              bufA[par][mt][ds], bufB[par][ds][ft], acc[mt][ft], 0, 0, 0);
  };

  load_batch(0, 0);
  for (int i = 0; i < 12; i++) {
    load_batch(2 * i + 1, 1);
    compute_batch(0);
    if (i < 11) load_batch(2 * i + 2, 0);
    compute_batch(1);
  }

  f32x4 bv = *reinterpret_cast<const f32x4*>(bias + 4 * n);

#pragma unroll
  for (int mt = 0; mt < 2; mt++) {
#pragma unroll
    for (int reg = 0; reg < 4; reg++) {
      int m  = q * 4 + reg;
      int v  = vbase + mt * 8 + (m >> 1);
      int bb = m & 1;
      if (v < NV) {
        f32x4 x;
#pragma unroll
        for (int ft = 0; ft < 4; ft++) {
          float t = acc[mt][ft][reg] + bv[ft];   // f = 4n+ft
          x[ft] = t > 0.f ? t : 0.f;
        }
        float* dst = out + (((bb * NV + v) * ND + l) * NFDIM) + 4 * n;
        __builtin_nontemporal_store(x, (f32x4*)dst);
      }
    }
  }
}

// Slow fp32 fallback (only if ws too small).
__global__ void fallback_kernel(const float* __restrict__ y, const int* __restrict__ ftv,
                                const int* __restrict__ ftd, const float* __restrict__ kern,
                                const float* __restrict__ bias, float* __restrict__ out) {
  int idx = blockIdx.x;               // b*NV*16 + v*16 + l
  int l = idx & 15;
  int v = (idx >> 4) % NV;
  int b = idx / (NV * ND);
  int f = threadIdx.x;
  float acc = 0.f;
  for (int r = 0; r < NR; r++)
    for (int d = 0; d < ND; d++) {
      int ii = (v * NR + r) * ND + d;
      int vv = ftv[ii];
      int dd = (ftd[ii] + l) & 15;
      int dp = (d - l) & 15;
      const float* yp = y + ((b * NV + vv) * ND + dd) * NC;
      const float* kp = kern + ((r * 16 + dp) * NC) * NFDIM + f;
#pragma unroll 8
      for (int c = 0; c < NC; c++) acc += yp[c] * kp[c * NFDIM];
    }
  float x = acc + bias[f];
  out[idx * NFDIM + f] = x > 0.f ? x : 0.f;
}

extern "C" void kernel_launch(void* const* d_in, const int* in_sizes, int n_in,
                              void* d_out, int out_size, void* d_ws, size_t ws_size,
                              hipStream_t stream) {
  const float* y    = (const float*)d_in[0];
  const int*   ftv  = (const int*)d_in[1];
  const int*   ftd  = (const int*)d_in[2];
  const float* kern = (const float*)d_in[3];
  const float* bias = (const float*)d_in[4];
  float* out = (float*)d_out;

  if (ws_size >= (size_t)WS_NEEDED) {
    char* ws = (char*)d_ws;
    unsigned short* yt = (unsigned short*)ws;
    unsigned short* kb = (unsigned short*)(ws + KB_OFF);

    prep_y<<<(NV * ND * BB * NC / 8 + 255) / 256, 256, 0, stream>>>(y, (u16x8*)yt);
    prep_kb<<<(48 * 4 * 64 + 255) / 256, 256, 0, stream>>>(kern, kb);
    // 938 m-groups (16 v each) x 4 l-groups = 3752 blocks x 4 waves
    sync_conv_main<<<3752, 256, 0, stream>>>(yt, kb, ftv, ftd, bias, out);
  } else {
    fallback_kernel<<<BB * NV * ND, NFDIM, 0, stream>>>(y, ftv, ftd, kern, bias, out);
  }
}